// Round 12
// baseline (312.139 us; speedup 1.0000x reference)
//
#include <hip/hip_runtime.h>
#include <hip/hip_bf16.h>

#define B_ 64
#define L_ 512
#define H_ 1024
#define A_ 1024

typedef short bf16x8 __attribute__((ext_vector_type(8)));
typedef float f32x4 __attribute__((ext_vector_type(4)));

__device__ __forceinline__ void gld16(const void* g, void* l) {
  __builtin_amdgcn_global_load_lds((const __attribute__((address_space(1))) void*)g,
                                   (__attribute__((address_space(3))) void*)l, 16, 0, 0);
}

__device__ __forceinline__ unsigned short f2bf(float f) {
  unsigned u = __builtin_bit_cast(unsigned, f);
  u = (u + 0x7fffu + ((u >> 16) & 1u)) >> 16;
  return (unsigned short)u;
}

__device__ __forceinline__ unsigned short cvtbf(float f) {
  __hip_bfloat16 b = __float2bfloat16(f);
  return __builtin_bit_cast(unsigned short, b);
}

__device__ __forceinline__ float fast_tanh(float x) {
  float e = __expf(2.f * x);
  float r = __builtin_amdgcn_rcpf(e + 1.f);
  return __builtin_fmaf(-2.f, r, 1.f);
}

// ---------- K0: Wt[a][h] = bf16(W[h][a]) ----------
__global__ __launch_bounds__(256) void wtrans_kernel(const float* __restrict__ W,
                                                     unsigned short* __restrict__ Wt) {
  __shared__ float tile[32][33];
  int tx = threadIdx.x & 31, ty = threadIdx.x >> 5;
  int a0 = (blockIdx.x & 31) << 5, h0 = (blockIdx.x >> 5) << 5;
#pragma unroll
  for (int i = 0; i < 4; ++i) {
    int h = ty + i * 8;
    tile[h][tx] = W[(size_t)(h0 + h) * A_ + a0 + tx];
  }
  __syncthreads();
#pragma unroll
  for (int i = 0; i < 4; ++i) {
    int a = ty + i * 8;
    Wt[(size_t)(a0 + a) * H_ + h0 + tx] = f2bf(tile[tx][a]);
  }
}

// ---------- K1: fused f32-A 8-phase proj: Pb = bf16(tanh(X @ Wt^T)[*diag]) ----
// 256x256 tile, 512 thr = 8 waves (2M x 4N), BK=32, 32 K-tiles.
// A staged RAW f32 via global_load_lds (no reg round-trip, no cvt pass);
// converted to bf16 in-register at fragment-read time (cvt_pk, ~16/phase).
// THREE-buffer LDS ring (A 3x32KB f32 + B 3x16KB bf16 = 144KB): stage kt+2
// during kt's phases -> prefetch distance 4 phases covers HBM latency.
// ckpt vmcnt(6) at K-tile end confirms buf[kt+1] (its 6 loads issued at kt-1).
// Phase = {ds_reads (+bq in ph0) | stage -> barrier -> 16 MFMA (setprio) ->
// [ckpt] -> barrier}; 2 phases/K-tile -> same 128-barrier budget as R11 proj8.
__global__ __launch_bounds__(512, 2) void projf_kernel(
    const float* __restrict__ Xlt, const float* __restrict__ Xrt,
    const unsigned short* __restrict__ Wt, const float* __restrict__ diag,
    unsigned short* __restrict__ Pb) {
  __shared__ float Af[3][256 * 32];           // 3 x 32 KB
  __shared__ unsigned short Bb[3][256 * 32];  // 3 x 16 KB
  int t = threadIdx.x;
  int lane = t & 63, wave = t >> 6;
  int wr = wave >> 2, wc = wave & 3;   // 2M x 4N; per-wave 128x64 out
  int l15 = lane & 15, l4 = lane >> 4;

  // XCD swizzle
  int bid = (int)blockIdx.x;           // 1024 blocks
  int x = bid & 7, k = bid >> 3;
  int mt = x + 8 * (k >> 2);           // [0,256)
  int nt = k & 3;
  int mrow0 = mt << 8, ncol0 = nt << 8;
  int isLt = (mt < 128);
  const float* X = isLt ? Xlt : Xrt;
  int xrow0 = (isLt ? mt : mt - 128) << 8;

  // A staging: 4 gld16/thread/K-tile. chunk ci = u*512+t -> row=ci>>3, c=ci&7
  // (8 chunks of 16B = 32 f32 per row). Source pre-swizzled: slot c holds
  // global chunk c ^ (r&7). LDS dest LINEAR (gld16 requirement).
  const float* gAsrc[4];
  int adst[4];
#pragma unroll
  for (int u = 0; u < 4; ++u) {
    int ci = u * 512 + t;
    int r = ci >> 3, c = ci & 7;
    gAsrc[u] = X + (size_t)(xrow0 + r) * H_ + ((c ^ (r & 7)) << 2);
    adst[u] = ci * 4;                  // float index
  }
  // B staging: 2 gld16/thread/K-tile. ci -> row=ci>>2, c=ci&3 (4x16B chunks).
  const unsigned short* gBsrc[2];
  int bdst[2];
#pragma unroll
  for (int u = 0; u < 2; ++u) {
    int ci = u * 512 + t;
    int r = ci >> 2, c = ci & 3;
    gBsrc[u] = Wt + (size_t)(ncol0 + r) * H_ + ((c ^ ((r >> 1) & 3)) << 3);
    bdst[u] = ci * 8;                  // ushort index
  }

#define STGA(buf, kt_) {                                   \
    gld16(gAsrc[0] + (kt_) * 32, &Af[buf][adst[0]]);       \
    gld16(gAsrc[1] + (kt_) * 32, &Af[buf][adst[1]]);       \
    gld16(gAsrc[2] + (kt_) * 32, &Af[buf][adst[2]]);       \
    gld16(gAsrc[3] + (kt_) * 32, &Af[buf][adst[3]]); }
#define STGB(buf, kt_) {                                   \
    gld16(gBsrc[0] + (kt_) * 32, &Bb[buf][bdst[0]]);       \
    gld16(gBsrc[1] + (kt_) * 32, &Bb[buf][bdst[1]]); }

  // fragment-read swizzles
  int s0 = ((2 * l4) ^ (l15 & 7)) * 4;       // f32 slot (float index), pair at ^4
  int rdB = (l4 ^ ((l15 >> 1) & 3)) * 8;     // bf16 slot (ushort index)

  f32x4 acc[8][4] = {};

  // prologue: kt0 -> buf0, kt1 -> buf1 (6 loads each)
  STGA(0, 0); STGB(0, 0);
  STGA(1, 1); STGB(1, 1);
  asm volatile("s_waitcnt vmcnt(6)" ::: "memory");
  asm volatile("s_barrier" ::: "memory");

  int cur = 0;
  for (int kt = 0; kt < 32; ++kt) {
    int nxt = cur + 2; if (nxt >= 3) nxt -= 3;   // (kt+2)%3
    bool st = (kt <= 29);
    const float* Ac = Af[cur];
    const unsigned short* Bc = Bb[cur];

    // ---- phase 0: quadrant 0 (wave rows 0..63) ----
    bf16x8 bq[4];
#pragma unroll
    for (int ni = 0; ni < 4; ++ni)
      bq[ni] = *(const bf16x8*)&Bc[(wc * 64 + ni * 16 + l15) * 32 + rdB];
    bf16x8 aq[4];
#pragma unroll
    for (int f = 0; f < 4; ++f) {
      const float* base = &Ac[(wr * 128 + f * 16 + l15) * 32];
      float4 v0 = *(const float4*)(base + s0);
      float4 v1 = *(const float4*)(base + (s0 ^ 4));
      bf16x8 a;
      a[0] = (short)cvtbf(v0.x); a[1] = (short)cvtbf(v0.y);
      a[2] = (short)cvtbf(v0.z); a[3] = (short)cvtbf(v0.w);
      a[4] = (short)cvtbf(v1.x); a[5] = (short)cvtbf(v1.y);
      a[6] = (short)cvtbf(v1.z); a[7] = (short)cvtbf(v1.w);
      aq[f] = a;
    }
    if (st) STGA(nxt, kt + 2);
    asm volatile("s_barrier" ::: "memory");
    __builtin_amdgcn_s_setprio(1);
#pragma unroll
    for (int f = 0; f < 4; ++f)
#pragma unroll
      for (int ni = 0; ni < 4; ++ni)
        acc[f][ni] = __builtin_amdgcn_mfma_f32_16x16x32_bf16(aq[f], bq[ni], acc[f][ni], 0, 0, 0);
    __builtin_amdgcn_s_setprio(0);
    asm volatile("s_barrier" ::: "memory");

    // ---- phase 1: quadrant 1 (wave rows 64..127) ----
#pragma unroll
    for (int f = 0; f < 4; ++f) {
      const float* base = &Ac[(wr * 128 + 64 + f * 16 + l15) * 32];
      float4 v0 = *(const float4*)(base + s0);
      float4 v1 = *(const float4*)(base + (s0 ^ 4));
      bf16x8 a;
      a[0] = (short)cvtbf(v0.x); a[1] = (short)cvtbf(v0.y);
      a[2] = (short)cvtbf(v0.z); a[3] = (short)cvtbf(v0.w);
      a[4] = (short)cvtbf(v1.x); a[5] = (short)cvtbf(v1.y);
      a[6] = (short)cvtbf(v1.z); a[7] = (short)cvtbf(v1.w);
      aq[f] = a;
    }
    if (st) STGB(nxt, kt + 2);
    asm volatile("s_barrier" ::: "memory");
    __builtin_amdgcn_s_setprio(1);
#pragma unroll
    for (int f = 0; f < 4; ++f)
#pragma unroll
      for (int ni = 0; ni < 4; ++ni)
        acc[4 + f][ni] = __builtin_amdgcn_mfma_f32_16x16x32_bf16(aq[f], bq[ni], acc[4 + f][ni], 0, 0, 0);
    __builtin_amdgcn_s_setprio(0);
    if (kt < 30)
      asm volatile("s_waitcnt vmcnt(6)" ::: "memory");   // buf[kt+1] confirmed
    else
      asm volatile("s_waitcnt vmcnt(0)" ::: "memory");
    asm volatile("s_barrier" ::: "memory");
    cur = (cur == 2) ? 0 : cur + 1;
  }
#undef STGA
#undef STGB

#pragma unroll
  for (int mi = 0; mi < 8; ++mi) {
#pragma unroll
    for (int ni = 0; ni < 4; ++ni) {
      int col = ncol0 + wc * 64 + ni * 16 + l15;
      float d = isLt ? diag[col] : 1.0f;
#pragma unroll
      for (int rr = 0; rr < 4; ++rr) {
        int row = mrow0 + wr * 128 + mi * 16 + l4 * 4 + rr;
        Pb[(size_t)row * A_ + col] = f2bf(fast_tanh(acc[mi][ni][rr]) * d);
      }
    }
  }
}

// ================= 8-phase conveyor macros (R11, proven) ===================
#define STG_FROM(gptr, Ls, buf, h, kt_) {                                  \
    const unsigned short* g_ = (gptr) + (size_t)(h) * 128 * H_ + (kt_) * 64; \
    gld16(g_, &Ls[buf][(h) * 8192 + lofs]);                                \
    gld16(g_ + (size_t)64 * H_, &Ls[buf][(h) * 8192 + 4096 + lofs]); }

#define LOAD_BQ(Bsrc, buf) { _Pragma("unroll") for (int ni = 0; ni < 4; ++ni) { \
    int brow = wc * 64 + ni * 16 + l15;                                    \
    bq[ni][0] = *(const bf16x8*)&Bsrc[buf][brow * 64 + rd0];               \
    bq[ni][1] = *(const bf16x8*)&Bsrc[buf][brow * 64 + rd1]; } }

#define PHASE(Asrc, q, buf, STAGE_OP, CKPT) {                              \
    bf16x8 aq0, aq1, aq2, aq3;                                             \
    { int ar = wr * 128 + (q) * 32 + l15;                                  \
      aq0 = *(const bf16x8*)&Asrc[buf][ar * 64 + rd0];                     \
      aq1 = *(const bf16x8*)&Asrc[buf][ar * 64 + rd1];                     \
      aq2 = *(const bf16x8*)&Asrc[buf][(ar + 16) * 64 + rd0];              \
      aq3 = *(const bf16x8*)&Asrc[buf][(ar + 16) * 64 + rd1]; }            \
    STAGE_OP;                                                              \
    asm volatile("s_barrier" ::: "memory");                                \
    __builtin_amdgcn_s_setprio(1);                                         \
    _Pragma("unroll") for (int ni = 0; ni < 4; ++ni) {                     \
      acc[(q)*2][ni] = __builtin_amdgcn_mfma_f32_16x16x32_bf16(            \
          aq0, bq[ni][0], acc[(q)*2][ni], 0, 0, 0);                        \
      acc[(q)*2][ni] = __builtin_amdgcn_mfma_f32_16x16x32_bf16(            \
          aq1, bq[ni][1], acc[(q)*2][ni], 0, 0, 0);                        \
      acc[(q)*2+1][ni] = __builtin_amdgcn_mfma_f32_16x16x32_bf16(          \
          aq2, bq[ni][0], acc[(q)*2+1][ni], 0, 0, 0);                      \
      acc[(q)*2+1][ni] = __builtin_amdgcn_mfma_f32_16x16x32_bf16(          \
          aq3, bq[ni][1], acc[(q)*2+1][ni], 0, 0, 0); }                    \
    __builtin_amdgcn_s_setprio(0);                                         \
    if (CKPT) asm volatile("s_waitcnt vmcnt(4)" ::: "memory");             \
    asm volatile("s_barrier" ::: "memory"); }

#define CONVEYOR(gA_, gB_)                                                 \
  STG_FROM(gB_, Bs, 0, 0, 0); STG_FROM(gB_, Bs, 0, 1, 0);                  \
  STG_FROM(gA_, As, 0, 0, 0); STG_FROM(gA_, As, 0, 1, 0);                  \
  STG_FROM(gB_, Bs, 1, 0, 1); STG_FROM(gB_, Bs, 1, 1, 1);                  \
  asm volatile("s_waitcnt vmcnt(4)" ::: "memory");                         \
  asm volatile("s_barrier" ::: "memory");                                  \
  for (int i = 0; i < 8; ++i) {                                            \
    int kt1 = 2 * i + 1;                                                   \
    int kt2 = (2 * i + 2) & 15, kt3 = (2 * i + 3) & 15;                    \
    LOAD_BQ(Bs, 0);                                                        \
    PHASE(As, 0, 0, STG_FROM(gA_, As, 1, 0, kt1), 0);                      \
    PHASE(As, 1, 0, STG_FROM(gA_, As, 1, 1, kt1), 0);                      \
    PHASE(As, 2, 0, STG_FROM(gB_, Bs, 0, 0, kt2), 0);                      \
    PHASE(As, 3, 0, STG_FROM(gB_, Bs, 0, 1, kt2), 1);                      \
    LOAD_BQ(Bs, 1);                                                        \
    PHASE(As, 0, 1, STG_FROM(gA_, As, 0, 0, kt2), 0);                      \
    PHASE(As, 1, 1, STG_FROM(gA_, As, 0, 1, kt2), 0);                      \
    PHASE(As, 2, 1, STG_FROM(gB_, Bs, 1, 0, kt3), 0);                      \
    PHASE(As, 3, 1, STG_FROM(gB_, Bs, 1, 1, kt3), 1);                      \
  }

// ---------- K2: 8-phase score: out[b][l][r] = (Plt.Prt^T) * ml * mr ----------
__global__ __launch_bounds__(512, 2) void score8_kernel(
    const unsigned short* __restrict__ Pb,
    const float* __restrict__ mask_lt, const float* __restrict__ mask_rt,
    float* __restrict__ out) {
  __shared__ unsigned short As[2][256 * 64];
  __shared__ unsigned short Bs[2][256 * 64];
  int t = threadIdx.x;
  int lane = t & 63, wave = t >> 6;
  int wr = wave >> 2, wc = wave & 3;
  int l15 = lane & 15, l4 = lane >> 4;

  int bid = (int)blockIdx.x;
  int x = bid & 7, k = bid >> 3;
  int pm = x + 8 * (k >> 1);           // [0,128)
  int b = pm >> 1, mt = pm & 1, nt = k & 1;

  int arow0 = b * 512 + mt * 256;
  int brow0 = 32768 + b * 512 + nt * 256;

  int rs = t >> 3, ss = t & 7;
  const unsigned short* gA = Pb + (size_t)(arow0 + rs) * H_ + ((ss ^ (rs & 7)) << 3);
  const unsigned short* gB = Pb + (size_t)(brow0 + rs) * H_ + ((ss ^ (rs & 7)) << 3);
  int lofs = (rs * 8 + ss) * 8;

  int rd0 = (l4 ^ (l15 & 7)) * 8;
  int rd1 = ((4 + l4) ^ (l15 & 7)) * 8;

  f32x4 acc[8][4] = {};
  bf16x8 bq[4][2];

  CONVEYOR(gA, gB);

  const float* mlp = mask_lt + b * L_;
  const float* mrp = mask_rt + b * L_;
  float* obase = out + (size_t)b * L_ * L_;
#pragma unroll
  for (int mi = 0; mi < 8; ++mi) {
#pragma unroll
    for (int ni = 0; ni < 4; ++ni) {
      int col = nt * 256 + wc * 64 + ni * 16 + l15;
      float mr = mrp[col];
#pragma unroll
      for (int rr = 0; rr < 4; ++rr) {
        int row = mt * 256 + wr * 128 + mi * 16 + l4 * 4 + rr;
        obase[(size_t)row * L_ + col] = acc[mi][ni][rr] * mlp[row] * mr;
      }
    }
  }
}

// ---------- K3: in-place row softmax over 512, then re-mask ----------
__global__ __launch_bounds__(256) void softmax_kernel(float* __restrict__ out,
                                                      const float* __restrict__ mask_lt,
                                                      const float* __restrict__ mask_rt) {
  int lane = threadIdx.x & 63, wave = threadIdx.x >> 6;
  int row = (int)blockIdx.x * 4 + wave;
  int b = row >> 9;
  float* p = out + (size_t)row * L_;
  float4 v0 = *(const float4*)(p + lane * 8);
  float4 v1 = *(const float4*)(p + lane * 8 + 4);
  float m = fmaxf(fmaxf(fmaxf(v0.x, v0.y), fmaxf(v0.z, v0.w)),
                  fmaxf(fmaxf(v1.x, v1.y), fmaxf(v1.z, v1.w)));
#pragma unroll
  for (int off = 32; off; off >>= 1) m = fmaxf(m, __shfl_xor(m, off));
  float e0 = __expf(v0.x - m), e1 = __expf(v0.y - m), e2 = __expf(v0.z - m), e3 = __expf(v0.w - m);
  float e4 = __expf(v1.x - m), e5 = __expf(v1.y - m), e6 = __expf(v1.z - m), e7 = __expf(v1.w - m);
  float s = ((e0 + e1) + (e2 + e3)) + ((e4 + e5) + (e6 + e7));
#pragma unroll
  for (int off = 32; off; off >>= 1) s += __shfl_xor(s, off);
  float sc = (1.0f / s) * mask_lt[row];
  const float* mrp = mask_rt + (b << 9) + lane * 8;
  float4 mr0 = *(const float4*)mrp;
  float4 mr1 = *(const float4*)(mrp + 4);
  float4 o0 = make_float4(e0 * sc * mr0.x, e1 * sc * mr0.y, e2 * sc * mr0.z, e3 * sc * mr0.w);
  float4 o1 = make_float4(e4 * sc * mr1.x, e5 * sc * mr1.y, e6 * sc * mr1.z, e7 * sc * mr1.w);
  *(float4*)(p + lane * 8) = o0;
  *(float4*)(p + lane * 8 + 4) = o1;
}

extern "C" void kernel_launch(void* const* d_in, const int* in_sizes, int n_in,
                              void* d_out, int out_size, void* d_ws, size_t ws_size,
                              hipStream_t stream) {
  const float* reps_lt = (const float*)d_in[0];
  const float* reps_rt = (const float*)d_in[1];
  const float* mask_lt = (const float*)d_in[2];
  const float* mask_rt = (const float*)d_in[3];
  const float* attn_w1 = (const float*)d_in[4];
  const float* diag    = (const float*)d_in[5];
  float* out = (float*)d_out;

  unsigned short* wt = (unsigned short*)d_ws;    // 2 MB
  unsigned short* pb = wt + (size_t)H_ * A_;     // 128 MB

  hipLaunchKernelGGL(wtrans_kernel, dim3(1024), dim3(256), 0, stream, attn_w1, wt);
  hipLaunchKernelGGL(projf_kernel, dim3(1024), dim3(512), 0, stream,
                     reps_lt, reps_rt, wt, diag, pb);
  hipLaunchKernelGGL(score8_kernel, dim3(256), dim3(512), 0, stream,
                     pb, mask_lt, mask_rt, out);
  hipLaunchKernelGGL(softmax_kernel, dim3(8192), dim3(256), 0, stream,
                     out, mask_lt, mask_rt);
}

// Round 14
// 295.449 us; speedup vs baseline: 1.0565x; 1.0565x over previous
//
#include <hip/hip_runtime.h>
#include <hip/hip_bf16.h>

#define B_ 64
#define L_ 512
#define H_ 1024
#define A_ 1024

typedef short bf16x8 __attribute__((ext_vector_type(8)));
typedef float f32x4 __attribute__((ext_vector_type(4)));

__device__ __forceinline__ void gld16(const void* g, void* l) {
  __builtin_amdgcn_global_load_lds((const __attribute__((address_space(1))) void*)g,
                                   (__attribute__((address_space(3))) void*)l, 16, 0, 0);
}

__device__ __forceinline__ unsigned short f2bf(float f) {
  unsigned u = __builtin_bit_cast(unsigned, f);
  u = (u + 0x7fffu + ((u >> 16) & 1u)) >> 16;
  return (unsigned short)u;
}

__device__ __forceinline__ unsigned short cvtbf(float f) {
  __hip_bfloat16 b = __float2bfloat16(f);
  return __builtin_bit_cast(unsigned short, b);
}

__device__ __forceinline__ float fast_tanh(float x) {
  float e = __expf(2.f * x);
  float r = __builtin_amdgcn_rcpf(e + 1.f);
  return __builtin_fmaf(-2.f, r, 1.f);
}

// ---------- K-1: Xb = bf16(concat(Xlt, Xrt)), streaming ----------
__global__ __launch_bounds__(256) void cvt_kernel(const float* __restrict__ lt,
                                                  const float* __restrict__ rt,
                                                  unsigned short* __restrict__ xb) {
  const size_t NC = (size_t)B_ * L_ * H_ / 8;
  size_t stride = (size_t)gridDim.x * blockDim.x;
  for (size_t c = (size_t)blockIdx.x * blockDim.x + threadIdx.x; c < 2 * NC; c += stride) {
    const float* src = (c < NC) ? (lt + c * 8) : (rt + (c - NC) * 8);
    float4 v0 = ((const float4*)src)[0];
    float4 v1 = ((const float4*)src)[1];
    bf16x8 o;
    o[0] = (short)cvtbf(v0.x); o[1] = (short)cvtbf(v0.y);
    o[2] = (short)cvtbf(v0.z); o[3] = (short)cvtbf(v0.w);
    o[4] = (short)cvtbf(v1.x); o[5] = (short)cvtbf(v1.y);
    o[6] = (short)cvtbf(v1.z); o[7] = (short)cvtbf(v1.w);
    *(bf16x8*)(xb + c * 8) = o;
  }
}

// ---------- K0: Wt[a][h] = bf16(W[h][a]) ----------
__global__ __launch_bounds__(256) void wtrans_kernel(const float* __restrict__ W,
                                                     unsigned short* __restrict__ Wt) {
  __shared__ float tile[32][33];
  int tx = threadIdx.x & 31, ty = threadIdx.x >> 5;
  int a0 = (blockIdx.x & 31) << 5, h0 = (blockIdx.x >> 5) << 5;
#pragma unroll
  for (int i = 0; i < 4; ++i) {
    int h = ty + i * 8;
    tile[h][tx] = W[(size_t)(h0 + h) * A_ + a0 + tx];
  }
  __syncthreads();
#pragma unroll
  for (int i = 0; i < 4; ++i) {
    int a = ty + i * 8;
    Wt[(size_t)(a0 + a) * H_ + h0 + tx] = f2bf(tile[tx][a]);
  }
}

// ================= 8-phase conveyor (R11 schedule, literal-kt unroll) =======
// Staging uses the PROVEN gld16(ptr) form (offset arg = 0); kt is a literal,
// so the compiler folds kt*128 bytes into the global_load's offset: field and
// CSEs the 8 half-tile base pointers -> near-zero VALU per stage.
// Barrier/vmcnt placement byte-identical to R11 (proven correct).
#define STG_A(buf, h, kt) {                                                 \
    gld16(gA##h    + (kt) * 64, &As[buf][(h) * 8192 + lofs]);               \
    gld16(gA##h##b + (kt) * 64, &As[buf][(h) * 8192 + 4096 + lofs]); }
#define STG_B(buf, h, kt) {                                                 \
    gld16(gB##h    + (kt) * 64, &Bs[buf][(h) * 8192 + lofs]);               \
    gld16(gB##h##b + (kt) * 64, &Bs[buf][(h) * 8192 + 4096 + lofs]); }

#define LOAD_BQ(buf) { _Pragma("unroll") for (int ni = 0; ni < 4; ++ni) {   \
    int brow = wc * 64 + ni * 16 + l15;                                     \
    bq[ni][0] = *(const bf16x8*)&Bs[buf][brow * 64 + rd0];                  \
    bq[ni][1] = *(const bf16x8*)&Bs[buf][brow * 64 + rd1]; } }

#define PHASE(q, buf, STAGE_OP, CKPT) {                                     \
    bf16x8 aq0, aq1, aq2, aq3;                                              \
    { int ar = wr * 128 + (q) * 32 + l15;                                   \
      aq0 = *(const bf16x8*)&As[buf][ar * 64 + rd0];                        \
      aq1 = *(const bf16x8*)&As[buf][ar * 64 + rd1];                        \
      aq2 = *(const bf16x8*)&As[buf][(ar + 16) * 64 + rd0];                 \
      aq3 = *(const bf16x8*)&As[buf][(ar + 16) * 64 + rd1]; }               \
    STAGE_OP;                                                               \
    asm volatile("s_barrier" ::: "memory");                                 \
    __builtin_amdgcn_s_setprio(1);                                          \
    _Pragma("unroll") for (int ni = 0; ni < 4; ++ni) {                      \
      acc[(q)*2][ni] = __builtin_amdgcn_mfma_f32_16x16x32_bf16(             \
          aq0, bq[ni][0], acc[(q)*2][ni], 0, 0, 0);                         \
      acc[(q)*2][ni] = __builtin_amdgcn_mfma_f32_16x16x32_bf16(             \
          aq1, bq[ni][1], acc[(q)*2][ni], 0, 0, 0);                         \
      acc[(q)*2+1][ni] = __builtin_amdgcn_mfma_f32_16x16x32_bf16(           \
          aq2, bq[ni][0], acc[(q)*2+1][ni], 0, 0, 0);                       \
      acc[(q)*2+1][ni] = __builtin_amdgcn_mfma_f32_16x16x32_bf16(           \
          aq3, bq[ni][1], acc[(q)*2+1][ni], 0, 0, 0); }                     \
    __builtin_amdgcn_s_setprio(0);                                          \
    if (CKPT) asm volatile("s_waitcnt vmcnt(4)" ::: "memory");              \
    asm volatile("s_barrier" ::: "memory"); }

#define CONV_ITER(kt1, kt2, kt3) {                                          \
    LOAD_BQ(0);                                                             \
    PHASE(0, 0, STG_A(1, 0, kt1), 0);                                       \
    PHASE(1, 0, STG_A(1, 1, kt1), 0);                                       \
    PHASE(2, 0, STG_B(0, 0, kt2), 0);                                       \
    PHASE(3, 0, STG_B(0, 1, kt2), 1);                                       \
    LOAD_BQ(1);                                                             \
    PHASE(0, 1, STG_A(0, 0, kt2), 0);                                       \
    PHASE(1, 1, STG_A(0, 1, kt2), 0);                                       \
    PHASE(2, 1, STG_B(1, 0, kt3), 0);                                       \
    PHASE(3, 1, STG_B(1, 1, kt3), 1); }

#define CONVEYOR_LIT()                                                      \
  STG_B(0, 0, 0); STG_B(0, 1, 0);                                           \
  STG_A(0, 0, 0); STG_A(0, 1, 0);                                           \
  STG_B(1, 0, 1); STG_B(1, 1, 1);                                           \
  asm volatile("s_waitcnt vmcnt(4)" ::: "memory");                          \
  asm volatile("s_barrier" ::: "memory");                                   \
  CONV_ITER(1, 2, 3)   CONV_ITER(3, 4, 5)   CONV_ITER(5, 6, 7)              \
  CONV_ITER(7, 8, 9)   CONV_ITER(9, 10, 11) CONV_ITER(11, 12, 13)           \
  CONV_ITER(13, 14, 15) CONV_ITER(15, 0, 1)

// ---------- K1: 256x256 8-phase proj: Pb = bf16(tanh(Xb@Wt^T)[*diag]) ------
__global__ __launch_bounds__(512, 2) void proj8_kernel(
    const unsigned short* __restrict__ Xb, const unsigned short* __restrict__ Wt,
    const float* __restrict__ diag, unsigned short* __restrict__ Pb) {
  __shared__ unsigned short As[2][256 * 64];
  __shared__ unsigned short Bs[2][256 * 64];
  int t = threadIdx.x;
  int lane = t & 63, wave = t >> 6;
  int wr = wave >> 2, wc = wave & 3;
  int l15 = lane & 15, l4 = lane >> 4;

  int bid = (int)blockIdx.x;           // 1024 blocks
  int x = bid & 7, k = bid >> 3;
  int mt = x + 8 * (k >> 2);           // [0,256)
  int nt = k & 3;
  int mrow0 = mt << 8, ncol0 = nt << 8;
  int isLt = (mt < 128);

  int rs = t >> 3, ss = t & 7;
  const unsigned short* gA0 = Xb + (size_t)(mrow0 + rs) * H_ + ((ss ^ (rs & 7)) << 3);
  const unsigned short* gA0b = gA0 + (size_t)64 * H_;
  const unsigned short* gA1  = gA0 + (size_t)128 * H_;
  const unsigned short* gA1b = gA0 + (size_t)192 * H_;
  const unsigned short* gB0 = Wt + (size_t)(ncol0 + rs) * H_ + ((ss ^ (rs & 7)) << 3);
  const unsigned short* gB0b = gB0 + (size_t)64 * H_;
  const unsigned short* gB1  = gB0 + (size_t)128 * H_;
  const unsigned short* gB1b = gB0 + (size_t)192 * H_;
  int lofs = (rs * 8 + ss) * 8;

  int rd0 = (l4 ^ (l15 & 7)) * 8;
  int rd1 = ((4 + l4) ^ (l15 & 7)) * 8;

  f32x4 acc[8][4] = {};
  bf16x8 bq[4][2];

  CONVEYOR_LIT();

#pragma unroll
  for (int mi = 0; mi < 8; ++mi) {
#pragma unroll
    for (int ni = 0; ni < 4; ++ni) {
      int col = ncol0 + wc * 64 + ni * 16 + l15;
      float d = isLt ? diag[col] : 1.0f;
#pragma unroll
      for (int rr = 0; rr < 4; ++rr) {
        int row = mrow0 + wr * 128 + mi * 16 + l4 * 4 + rr;
        Pb[(size_t)row * A_ + col] = f2bf(fast_tanh(acc[mi][ni][rr]) * d);
      }
    }
  }
}

// ---------- K2: 8-phase score: out[b][l][r] = (Plt.Prt^T) * ml * mr ----------
__global__ __launch_bounds__(512, 2) void score8_kernel(
    const unsigned short* __restrict__ Pb,
    const float* __restrict__ mask_lt, const float* __restrict__ mask_rt,
    float* __restrict__ out) {
  __shared__ unsigned short As[2][256 * 64];
  __shared__ unsigned short Bs[2][256 * 64];
  int t = threadIdx.x;
  int lane = t & 63, wave = t >> 6;
  int wr = wave >> 2, wc = wave & 3;
  int l15 = lane & 15, l4 = lane >> 4;

  int bid = (int)blockIdx.x;           // 256 blocks
  int x = bid & 7, k = bid >> 3;
  int pm = x + 8 * (k >> 1);           // [0,128)
  int b = pm >> 1, mt = pm & 1, nt = k & 1;

  int arow0 = b * 512 + mt * 256;
  int brow0 = 32768 + b * 512 + nt * 256;

  int rs = t >> 3, ss = t & 7;
  const unsigned short* gA0 = Pb + (size_t)(arow0 + rs) * H_ + ((ss ^ (rs & 7)) << 3);
  const unsigned short* gA0b = gA0 + (size_t)64 * H_;
  const unsigned short* gA1  = gA0 + (size_t)128 * H_;
  const unsigned short* gA1b = gA0 + (size_t)192 * H_;
  const unsigned short* gB0 = Pb + (size_t)(brow0 + rs) * H_ + ((ss ^ (rs & 7)) << 3);
  const unsigned short* gB0b = gB0 + (size_t)64 * H_;
  const unsigned short* gB1  = gB0 + (size_t)128 * H_;
  const unsigned short* gB1b = gB0 + (size_t)192 * H_;
  int lofs = (rs * 8 + ss) * 8;

  int rd0 = (l4 ^ (l15 & 7)) * 8;
  int rd1 = ((4 + l4) ^ (l15 & 7)) * 8;

  f32x4 acc[8][4] = {};
  bf16x8 bq[4][2];

  CONVEYOR_LIT();

  const float* mlp = mask_lt + b * L_;
  const float* mrp = mask_rt + b * L_;
  float* obase = out + (size_t)b * L_ * L_;
#pragma unroll
  for (int mi = 0; mi < 8; ++mi) {
#pragma unroll
    for (int ni = 0; ni < 4; ++ni) {
      int col = nt * 256 + wc * 64 + ni * 16 + l15;
      float mr = mrp[col];
#pragma unroll
      for (int rr = 0; rr < 4; ++rr) {
        int row = mt * 256 + wr * 128 + mi * 16 + l4 * 4 + rr;
        obase[(size_t)row * L_ + col] = acc[mi][ni][rr] * mlp[row] * mr;
      }
    }
  }
}

// ---------- K3: in-place row softmax over 512, then re-mask ----------
__global__ __launch_bounds__(256) void softmax_kernel(float* __restrict__ out,
                                                      const float* __restrict__ mask_lt,
                                                      const float* __restrict__ mask_rt) {
  int lane = threadIdx.x & 63, wave = threadIdx.x >> 6;
  int row = (int)blockIdx.x * 4 + wave;
  int b = row >> 9;
  float* p = out + (size_t)row * L_;
  float4 v0 = *(const float4*)(p + lane * 8);
  float4 v1 = *(const float4*)(p + lane * 8 + 4);
  float m = fmaxf(fmaxf(fmaxf(v0.x, v0.y), fmaxf(v0.z, v0.w)),
                  fmaxf(fmaxf(v1.x, v1.y), fmaxf(v1.z, v1.w)));
#pragma unroll
  for (int off = 32; off; off >>= 1) m = fmaxf(m, __shfl_xor(m, off));
  float e0 = __expf(v0.x - m), e1 = __expf(v0.y - m), e2 = __expf(v0.z - m), e3 = __expf(v0.w - m);
  float e4 = __expf(v1.x - m), e5 = __expf(v1.y - m), e6 = __expf(v1.z - m), e7 = __expf(v1.w - m);
  float s = ((e0 + e1) + (e2 + e3)) + ((e4 + e5) + (e6 + e7));
#pragma unroll
  for (int off = 32; off; off >>= 1) s += __shfl_xor(s, off);
  float sc = (1.0f / s) * mask_lt[row];
  const float* mrp = mask_rt + (b << 9) + lane * 8;
  float4 mr0 = *(const float4*)mrp;
  float4 mr1 = *(const float4*)(mrp + 4);
  float4 o0 = make_float4(e0 * sc * mr0.x, e1 * sc * mr0.y, e2 * sc * mr0.z, e3 * sc * mr0.w);
  float4 o1 = make_float4(e4 * sc * mr1.x, e5 * sc * mr1.y, e6 * sc * mr1.z, e7 * sc * mr1.w);
  *(float4*)(p + lane * 8) = o0;
  *(float4*)(p + lane * 8 + 4) = o1;
}

extern "C" void kernel_launch(void* const* d_in, const int* in_sizes, int n_in,
                              void* d_out, int out_size, void* d_ws, size_t ws_size,
                              hipStream_t stream) {
  const float* reps_lt = (const float*)d_in[0];
  const float* reps_rt = (const float*)d_in[1];
  const float* mask_lt = (const float*)d_in[2];
  const float* mask_rt = (const float*)d_in[3];
  const float* attn_w1 = (const float*)d_in[4];
  const float* diag    = (const float*)d_in[5];
  float* out = (float*)d_out;

  unsigned short* wt = (unsigned short*)d_ws;           // 2 MB
  unsigned short* pb = wt + (size_t)H_ * A_;            // 128 MB
  unsigned short* xb = pb + (size_t)B_ * L_ * A_ * 2;   // 128 MB

  hipLaunchKernelGGL(wtrans_kernel, dim3(1024), dim3(256), 0, stream, attn_w1, wt);
  hipLaunchKernelGGL(cvt_kernel, dim3(8192), dim3(256), 0, stream,
                     reps_lt, reps_rt, xb);
  hipLaunchKernelGGL(proj8_kernel, dim3(1024), dim3(512), 0, stream,
                     xb, wt, diag, pb);
  hipLaunchKernelGGL(score8_kernel, dim3(256), dim3(512), 0, stream,
                     pb, mask_lt, mask_rt, out);
  hipLaunchKernelGGL(softmax_kernel, dim3(8192), dim3(256), 0, stream,
                     out, mask_lt, mask_rt);
}